// Round 1
// baseline (1343.083 us; speedup 1.0000x reference)
//
#include <hip/hip_runtime.h>
#include <math.h>

#define N_NODES 100000
#define N_RELS  500
#define DIM     64
#define N_EDGES 1000000
#define SLOPE   0.01f
#define RSUB    16   // blocks per relation in pooling

// ---------------------------------------------------------------------------
// K0: fold the small matrices.
//  MU[j][i] = sum_k W_fc[j,k]     * W_ent[k,i]    (A @ W_ent)
//  MV[j][i] = sum_k W_fc[j,64+k]  * W_ent[k,i]
//  MW[j][i] = sum_k W_fc[j,128+k] * W_relL[k,i]
//  MQ[j][i] = sum_k W_rel2[j,k]   * W_relL[k,i]
//  dU = b_ent@A.T, dV = b_ent@B.T, dW = b_relL@C.T + b_fc, dQ = b_relL@W_rel2.T + b_rel2
// ---------------------------------------------------------------------------
__global__ void k_fold(const float* __restrict__ W_ent, const float* __restrict__ b_ent,
                       const float* __restrict__ W_relL, const float* __restrict__ b_relL,
                       const float* __restrict__ W_rel2, const float* __restrict__ b_rel2,
                       const float* __restrict__ W_fc, const float* __restrict__ b_fc,
                       float* __restrict__ MU, float* __restrict__ MV,
                       float* __restrict__ MW, float* __restrict__ MQ,
                       float* __restrict__ dU, float* __restrict__ dV,
                       float* __restrict__ dW, float* __restrict__ dQ) {
    int idx = blockIdx.x * 256 + threadIdx.x;
    if (idx < 4 * 4096) {
        int mat = idx >> 12;
        int rem = idx & 4095;
        int j = rem >> 6;   // output dim
        int i = rem & 63;   // input dim
        float s = 0.f;
        if (mat == 0) { for (int k = 0; k < 64; k++) s += W_fc[j*192 + k]       * W_ent[k*64 + i];  MU[j*64 + i] = s; }
        else if (mat == 1) { for (int k = 0; k < 64; k++) s += W_fc[j*192 + 64 + k]  * W_ent[k*64 + i];  MV[j*64 + i] = s; }
        else if (mat == 2) { for (int k = 0; k < 64; k++) s += W_fc[j*192 + 128 + k] * W_relL[k*64 + i]; MW[j*64 + i] = s; }
        else               { for (int k = 0; k < 64; k++) s += W_rel2[j*64 + k]      * W_relL[k*64 + i]; MQ[j*64 + i] = s; }
    } else if (idx < 4 * 4096 + 256) {
        int rem = idx - 4 * 4096;
        int vec = rem >> 6;
        int j = rem & 63;
        float s = 0.f;
        if (vec == 0)      { for (int k = 0; k < 64; k++) s += b_ent[k]  * W_fc[j*192 + k];       dU[j] = s; }
        else if (vec == 1) { for (int k = 0; k < 64; k++) s += b_ent[k]  * W_fc[j*192 + 64 + k];  dV[j] = s; }
        else if (vec == 2) { s = b_fc[j];   for (int k = 0; k < 64; k++) s += b_relL[k] * W_fc[j*192 + 128 + k]; dW[j] = s; }
        else               { s = b_rel2[j]; for (int k = 0; k < 64; k++) s += b_relL[k] * W_rel2[j*64 + k];      dQ[j] = s; }
    }
}

// ---------------------------------------------------------------------------
// K1: per-node projections. Wave per node; lane j holds row j of MU/MV in
// 128 VGPRs (loaded once per block). U goes directly into d_out (h buffer).
// us[n] = dot(U[n], w_a), vs[n] = dot(V[n], w_a).
// ---------------------------------------------------------------------------
__global__ __launch_bounds__(256, 2) void k_node(const float* __restrict__ ent,
        const float* __restrict__ MU, const float* __restrict__ MV,
        const float* __restrict__ dU, const float* __restrict__ dV,
        const float* __restrict__ W_a,
        float* __restrict__ Uout, float* __restrict__ V,
        float* __restrict__ us, float* __restrict__ vs) {
    int lane = threadIdx.x & 63;
    int wv = threadIdx.x >> 6;
    float mu[64], mv[64];
    #pragma unroll
    for (int i = 0; i < 64; i++) { mu[i] = MU[lane*64 + i]; mv[i] = MV[lane*64 + i]; }
    float du = dU[lane], dv = dV[lane], wa = W_a[lane];
    for (int n = blockIdx.x * 4 + wv; n < N_NODES; n += gridDim.x * 4) {
        float e = ent[(size_t)n * 64 + lane];
        float u = du, v = dv;
        #pragma unroll
        for (int i = 0; i < 64; i++) {
            float ei = __shfl(e, i, 64);
            u += ei * mu[i];
            v += ei * mv[i];
        }
        Uout[(size_t)n * 64 + lane] = u;
        V[(size_t)n * 64 + lane] = v;
        float tu = u * wa, tv = v * wa;
        #pragma unroll
        for (int o = 32; o; o >>= 1) { tu += __shfl_xor(tu, o, 64); tv += __shfl_xor(tv, o, 64); }
        if (lane == 0) { us[n] = tu; vs[n] = tv; }
    }
}

// K2: per-relation projections (Wr includes b_fc; Q = rel2 table; ws scalar).
__global__ __launch_bounds__(256, 2) void k_relproj(const float* __restrict__ relE,
        const float* __restrict__ MW, const float* __restrict__ MQ,
        const float* __restrict__ dW, const float* __restrict__ dQ,
        const float* __restrict__ W_a,
        float* __restrict__ Wr, float* __restrict__ Qr, float* __restrict__ wsr) {
    int lane = threadIdx.x & 63;
    int wv = threadIdx.x >> 6;
    float mw[64], mq[64];
    #pragma unroll
    for (int i = 0; i < 64; i++) { mw[i] = MW[lane*64 + i]; mq[i] = MQ[lane*64 + i]; }
    float dw = dW[lane], dq = dQ[lane], wa = W_a[lane];
    int r = blockIdx.x * 4 + wv;
    if (r >= N_RELS) return;
    float e = relE[(size_t)r * 64 + lane];
    float w = dw, q = dq;
    #pragma unroll
    for (int i = 0; i < 64; i++) {
        float ei = __shfl(e, i, 64);
        w += ei * mw[i];
        q += ei * mq[i];
    }
    Wr[(size_t)r * 64 + lane] = w;
    Qr[(size_t)r * 64 + lane] = q;
    float tw = w * wa;
    #pragma unroll
    for (int o = 32; o; o >>= 1) tw += __shfl_xor(tw, o, 64);
    if (lane == 0) wsr[r] = tw;
}

__global__ void k_zero(int* __restrict__ a, int n) {
    int g = blockIdx.x * 256 + threadIdx.x;
    if (g < n) a[g] = 0;
}

__global__ void k_hist(const int* __restrict__ src, const int* __restrict__ rel,
                       int* __restrict__ cnt_src, int* __restrict__ cnt_rel) {
    int g = blockIdx.x * 256 + threadIdx.x;
    if (g < N_EDGES) {
        atomicAdd(&cnt_src[src[g]], 1);
        atomicAdd(&cnt_rel[rel[g]], 1);
    }
}

// exclusive scan of cnt over chunks of 1024; partials[b] = chunk total
__global__ void k_scan_local(const int* __restrict__ cnt, int* __restrict__ start,
                             int* __restrict__ partials, int n) {
    __shared__ int tot[256];
    int base = blockIdx.x * 1024;
    int t = threadIdx.x;
    int myv[4];
    int mySum = 0;
    for (int q = 0; q < 4; q++) {
        int g = base + t * 4 + q;
        int v = (g < n) ? cnt[g] : 0;
        myv[q] = v; mySum += v;
    }
    tot[t] = mySum;
    __syncthreads();
    for (int o = 1; o < 256; o <<= 1) {
        int v = (t >= o) ? tot[t - o] : 0;
        __syncthreads();
        tot[t] += v;
        __syncthreads();
    }
    int run = tot[t] - mySum;
    for (int q = 0; q < 4; q++) {
        int g = base + t * 4 + q;
        if (g < n) start[g] = run;
        run += myv[q];
    }
    if (t == 255) partials[blockIdx.x] = tot[255];
}

__global__ void k_scan_part(int* __restrict__ partials, int n) {
    if (threadIdx.x == 0 && blockIdx.x == 0) {
        int run = 0;
        for (int i = 0; i < n; i++) { int v = partials[i]; partials[i] = run; run += v; }
    }
}

__global__ void k_scan_add(int* __restrict__ start, const int* __restrict__ partials,
                           int* __restrict__ ctr, int n) {
    int g = blockIdx.x * 256 + threadIdx.x;
    if (g < n) {
        int v = start[g] + partials[g >> 10];
        start[g] = v;
        ctr[g] = v;
    }
}

__global__ void k_scan_rel(const int* __restrict__ cnt, int* __restrict__ start, int* __restrict__ ctr) {
    if (threadIdx.x == 0 && blockIdx.x == 0) {
        int run = 0;
        for (int i = 0; i < N_RELS; i++) { start[i] = run; ctr[i] = run; run += cnt[i]; }
    }
}

__global__ void k_scatter(const int* __restrict__ src, const int* __restrict__ rel,
                          int* __restrict__ ctr_src, int* __restrict__ ctr_rel,
                          int* __restrict__ sorted_src, int* __restrict__ sorted_rel) {
    int g = blockIdx.x * 256 + threadIdx.x;
    if (g < N_EDGES) {
        int p = atomicAdd(&ctr_src[src[g]], 1);
        sorted_src[p] = g;
        int p2 = atomicAdd(&ctr_rel[rel[g]], 1);
        sorted_rel[p2] = g;
    }
}

// ---------------------------------------------------------------------------
// K6: fused scatter-softmax + neighbor aggregation. Wave per source node.
// h[n] = U[n] + (sum_e b_e*(V[dst_e]+Wr[rel_e])) / (sum_e b_e);  h pre-holds U.
// ---------------------------------------------------------------------------
__global__ __launch_bounds__(256) void k_attn(const int* __restrict__ sorted_src,
        const int* __restrict__ start_src, const int* __restrict__ cnt_src,
        const int* __restrict__ dst, const int* __restrict__ rel,
        const float* __restrict__ us, const float* __restrict__ vs,
        const float* __restrict__ wsr, const float* __restrict__ V,
        const float* __restrict__ Wr, const float* __restrict__ b_a_p,
        float* __restrict__ h) {
    int lane = threadIdx.x & 63;
    int wv = threadIdx.x >> 6;
    int n = blockIdx.x * 4 + wv;
    if (n >= N_NODES) return;
    int st = start_src[n];
    int cnt = cnt_src[n];
    if (cnt == 0) { h[(size_t)n * 64 + lane] = 0.f; return; }
    float ba = b_a_p[0];
    float usn = us[n];
    // pass 1: b_sum (lane-parallel over edges)
    float bp = 0.f;
    for (int k = lane; k < cnt; k += 64) {
        int e = sorted_src[st + k];
        float s = usn + vs[dst[e]] + wsr[rel[e]] + ba;
        s = s > 0.f ? s : SLOPE * s;
        bp += expf(s);
    }
    #pragma unroll
    for (int o = 32; o; o >>= 1) bp += __shfl_xor(bp, o, 64);
    float inv = 1.f / bp;
    // pass 2: vector accumulation (lane = dim)
    float acc = 0.f;
    for (int k = 0; k < cnt; k++) {
        int e = sorted_src[st + k];
        int d = dst[e];
        int r = rel[e];
        float s = usn + vs[d] + wsr[r] + ba;
        s = s > 0.f ? s : SLOPE * s;
        float b = expf(s);
        acc += b * (V[(size_t)d * 64 + lane] + Wr[(size_t)r * 64 + lane]);
    }
    float u = h[(size_t)n * 64 + lane];
    h[(size_t)n * 64 + lane] = u + acc * inv;
}

// ---------------------------------------------------------------------------
// K7: relation pooling partials. RSUB blocks per relation; threads 0..127 do
// even edges (64 dims h[src] | 64 dims h[dst]), 128..255 odd edges; LDS
// reduce, then one atomicAdd per (r, dim) per block.
// ---------------------------------------------------------------------------
__global__ __launch_bounds__(256) void k_relpool(const int* __restrict__ sorted_rel,
        const int* __restrict__ start_rel, const int* __restrict__ cnt_rel,
        const int* __restrict__ src, const int* __restrict__ dst,
        const float* __restrict__ h, float* __restrict__ acc_rel) {
    int r = blockIdx.x / RSUB;
    int sub = blockIdx.x % RSUB;
    int st = start_rel[r];
    int cnt = cnt_rel[r];
    int t = threadIdx.x;
    int half = t >> 7;     // 0 / 1
    int ld = t & 127;      // 0..127
    float a = 0.f;
    for (int k = half + 2 * sub; k < cnt; k += 2 * RSUB) {
        int e = sorted_rel[st + k];
        int idx = (ld < 64) ? src[e] : dst[e];
        a += h[(size_t)idx * 64 + (ld & 63)];
    }
    __shared__ float sums[256];
    sums[t] = a;
    __syncthreads();
    if (t < 128) atomicAdd(&acc_rel[r * 128 + t], sums[t] + sums[t + 128]);
}

// K8: mean + h_rel = mean @ W_rel3.T + b_rel3
__global__ void k_relfin(const float* __restrict__ acc_rel, const int* __restrict__ cnt_rel,
                         const float* __restrict__ Qr, const float* __restrict__ W_rel3,
                         const float* __restrict__ b_rel3, float* __restrict__ out) {
    int g = blockIdx.x * 256 + threadIdx.x;
    if (g >= N_RELS * 64) return;
    int r = g >> 6;
    int j = g & 63;
    int cnt = cnt_rel[r];
    float invc = 1.f / (float)(cnt > 0 ? cnt : 1);
    float s = b_rel3[j];
    for (int k = 0; k < 128; k++) s += acc_rel[r * 128 + k] * invc * W_rel3[j * 192 + k];
    if (cnt > 0)
        for (int k = 0; k < 64; k++) s += Qr[r * 64 + k] * W_rel3[j * 192 + 128 + k];
    out[g] = s;
}

extern "C" void kernel_launch(void* const* d_in, const int* in_sizes, int n_in,
                              void* d_out, int out_size, void* d_ws, size_t ws_size,
                              hipStream_t stream) {
    const float* ent    = (const float*)d_in[0];
    const float* relE   = (const float*)d_in[1];
    const float* W_ent  = (const float*)d_in[2];
    const float* b_ent  = (const float*)d_in[3];
    const float* W_relL = (const float*)d_in[4];
    const float* b_relL = (const float*)d_in[5];
    const float* W_rel2 = (const float*)d_in[6];
    const float* b_rel2 = (const float*)d_in[7];
    const float* W_rel3 = (const float*)d_in[8];
    const float* b_rel3 = (const float*)d_in[9];
    const float* W_a    = (const float*)d_in[10];
    const float* b_a    = (const float*)d_in[11];
    const float* W_fc   = (const float*)d_in[12];
    const float* b_fc   = (const float*)d_in[13];
    const int* src = (const int*)d_in[14];
    const int* dst = (const int*)d_in[15];
    const int* rel = (const int*)d_in[16];
    float* out = (float*)d_out;

    char* ws = (char*)d_ws;
    size_t off = 0;
    auto alloc = [&](size_t bytes) -> void* {
        void* p = ws + off;
        off += (bytes + 255) & ~(size_t)255;
        return p;
    };
    float* MU  = (float*)alloc(4096 * 4);
    float* MV  = (float*)alloc(4096 * 4);
    float* MW  = (float*)alloc(4096 * 4);
    float* MQ  = (float*)alloc(4096 * 4);
    float* dU  = (float*)alloc(64 * 4);
    float* dV  = (float*)alloc(64 * 4);
    float* dW  = (float*)alloc(64 * 4);
    float* dQ  = (float*)alloc(64 * 4);
    float* V   = (float*)alloc((size_t)N_NODES * 64 * 4);
    float* us  = (float*)alloc((size_t)N_NODES * 4);
    float* vs  = (float*)alloc((size_t)N_NODES * 4);
    float* Wr  = (float*)alloc((size_t)N_RELS * 64 * 4);
    float* Qr  = (float*)alloc((size_t)N_RELS * 64 * 4);
    float* wsr = (float*)alloc((size_t)N_RELS * 4);
    int* cnt_src   = (int*)alloc((size_t)N_NODES * 4);
    int* start_src = (int*)alloc((size_t)N_NODES * 4);
    int* ctr_src   = (int*)alloc((size_t)N_NODES * 4);
    int* partials  = (int*)alloc(128 * 4);
    int* cnt_rel   = (int*)alloc((size_t)N_RELS * 4);
    int* start_rel = (int*)alloc((size_t)N_RELS * 4);
    int* ctr_rel   = (int*)alloc((size_t)N_RELS * 4);
    int* sorted_src = (int*)alloc((size_t)N_EDGES * 4);
    int* sorted_rel = (int*)alloc((size_t)N_EDGES * 4);
    float* acc_rel  = (float*)alloc((size_t)N_RELS * 128 * 4);

    // zero the histogram / accumulator scratch (ws is poisoned 0xAA each call)
    k_zero<<<(N_NODES + 255) / 256, 256, 0, stream>>>(cnt_src, N_NODES);
    k_zero<<<(N_RELS + 255) / 256, 256, 0, stream>>>(cnt_rel, N_RELS);
    k_zero<<<(N_RELS * 128 + 255) / 256, 256, 0, stream>>>((int*)acc_rel, N_RELS * 128);

    k_fold<<<65, 256, 0, stream>>>(W_ent, b_ent, W_relL, b_relL, W_rel2, b_rel2,
                                   W_fc, b_fc, MU, MV, MW, MQ, dU, dV, dW, dQ);
    k_node<<<1024, 256, 0, stream>>>(ent, MU, MV, dU, dV, W_a, out, V, us, vs);
    k_relproj<<<125, 256, 0, stream>>>(relE, MW, MQ, dW, dQ, W_a, Wr, Qr, wsr);
    k_hist<<<(N_EDGES + 255) / 256, 256, 0, stream>>>(src, rel, cnt_src, cnt_rel);
    k_scan_local<<<98, 256, 0, stream>>>(cnt_src, start_src, partials, N_NODES);
    k_scan_part<<<1, 64, 0, stream>>>(partials, 98);
    k_scan_add<<<(N_NODES + 255) / 256, 256, 0, stream>>>(start_src, partials, ctr_src, N_NODES);
    k_scan_rel<<<1, 64, 0, stream>>>(cnt_rel, start_rel, ctr_rel);
    k_scatter<<<(N_EDGES + 255) / 256, 256, 0, stream>>>(src, rel, ctr_src, ctr_rel,
                                                         sorted_src, sorted_rel);
    k_attn<<<N_NODES / 4, 256, 0, stream>>>(sorted_src, start_src, cnt_src, dst, rel,
                                            us, vs, wsr, V, Wr, b_a, out);
    k_relpool<<<N_RELS * RSUB, 256, 0, stream>>>(sorted_rel, start_rel, cnt_rel,
                                                 src, dst, out, acc_rel);
    k_relfin<<<(N_RELS * 64 + 255) / 256, 256, 0, stream>>>(acc_rel, cnt_rel, Qr, W_rel3,
                                                            b_rel3, out + (size_t)N_NODES * 64);
}

// Round 2
// 678.211 us; speedup vs baseline: 1.9803x; 1.9803x over previous
//
#include <hip/hip_runtime.h>
#include <math.h>

#define N_NODES 100000
#define N_RELS  500
#define DIM     64
#define N_EDGES 1000000
#define SLOPE   0.01f
#define RSUB    16      // blocks per relation in pooling
#define SC_EDGES 8192   // edges per block in hist/scatter partition
#define NB_E    123     // ceil(N_EDGES / SC_EDGES)

// ---------------------------------------------------------------------------
// K0: fold the small matrices (see R0 notes).
// ---------------------------------------------------------------------------
__global__ void k_fold(const float* __restrict__ W_ent, const float* __restrict__ b_ent,
                       const float* __restrict__ W_relL, const float* __restrict__ b_relL,
                       const float* __restrict__ W_rel2, const float* __restrict__ b_rel2,
                       const float* __restrict__ W_fc, const float* __restrict__ b_fc,
                       float* __restrict__ MU, float* __restrict__ MV,
                       float* __restrict__ MW, float* __restrict__ MQ,
                       float* __restrict__ dU, float* __restrict__ dV,
                       float* __restrict__ dW, float* __restrict__ dQ) {
    int idx = blockIdx.x * 256 + threadIdx.x;
    if (idx < 4 * 4096) {
        int mat = idx >> 12;
        int rem = idx & 4095;
        int j = rem >> 6;
        int i = rem & 63;
        float s = 0.f;
        if (mat == 0) { for (int k = 0; k < 64; k++) s += W_fc[j*192 + k]       * W_ent[k*64 + i];  MU[j*64 + i] = s; }
        else if (mat == 1) { for (int k = 0; k < 64; k++) s += W_fc[j*192 + 64 + k]  * W_ent[k*64 + i];  MV[j*64 + i] = s; }
        else if (mat == 2) { for (int k = 0; k < 64; k++) s += W_fc[j*192 + 128 + k] * W_relL[k*64 + i]; MW[j*64 + i] = s; }
        else               { for (int k = 0; k < 64; k++) s += W_rel2[j*64 + k]      * W_relL[k*64 + i]; MQ[j*64 + i] = s; }
    } else if (idx < 4 * 4096 + 256) {
        int rem = idx - 4 * 4096;
        int vec = rem >> 6;
        int j = rem & 63;
        float s = 0.f;
        if (vec == 0)      { for (int k = 0; k < 64; k++) s += b_ent[k]  * W_fc[j*192 + k];       dU[j] = s; }
        else if (vec == 1) { for (int k = 0; k < 64; k++) s += b_ent[k]  * W_fc[j*192 + 64 + k];  dV[j] = s; }
        else if (vec == 2) { s = b_fc[j];   for (int k = 0; k < 64; k++) s += b_relL[k] * W_fc[j*192 + 128 + k]; dW[j] = s; }
        else               { s = b_rel2[j]; for (int k = 0; k < 64; k++) s += b_relL[k] * W_rel2[j*64 + k];      dQ[j] = s; }
    }
}

// ---------------------------------------------------------------------------
// K1: per-node projections (wave per node, weights in VGPRs).
// ---------------------------------------------------------------------------
__global__ __launch_bounds__(256, 2) void k_node(const float* __restrict__ ent,
        const float* __restrict__ MU, const float* __restrict__ MV,
        const float* __restrict__ dU, const float* __restrict__ dV,
        const float* __restrict__ W_a,
        float* __restrict__ Uout, float* __restrict__ V,
        float* __restrict__ us, float* __restrict__ vs) {
    int lane = threadIdx.x & 63;
    int wv = threadIdx.x >> 6;
    float mu[64], mv[64];
    #pragma unroll
    for (int i = 0; i < 64; i++) { mu[i] = MU[lane*64 + i]; mv[i] = MV[lane*64 + i]; }
    float du = dU[lane], dv = dV[lane], wa = W_a[lane];
    for (int n = blockIdx.x * 4 + wv; n < N_NODES; n += gridDim.x * 4) {
        float e = ent[(size_t)n * 64 + lane];
        float u = du, v = dv;
        #pragma unroll
        for (int i = 0; i < 64; i++) {
            float ei = __shfl(e, i, 64);
            u += ei * mu[i];
            v += ei * mv[i];
        }
        Uout[(size_t)n * 64 + lane] = u;
        V[(size_t)n * 64 + lane] = v;
        float tu = u * wa, tv = v * wa;
        #pragma unroll
        for (int o = 32; o; o >>= 1) { tu += __shfl_xor(tu, o, 64); tv += __shfl_xor(tv, o, 64); }
        if (lane == 0) { us[n] = tu; vs[n] = tv; }
    }
}

// K2: per-relation projections.
__global__ __launch_bounds__(256, 2) void k_relproj(const float* __restrict__ relE,
        const float* __restrict__ MW, const float* __restrict__ MQ,
        const float* __restrict__ dW, const float* __restrict__ dQ,
        const float* __restrict__ W_a,
        float* __restrict__ Wr, float* __restrict__ Qr, float* __restrict__ wsr) {
    int lane = threadIdx.x & 63;
    int wv = threadIdx.x >> 6;
    float mw[64], mq[64];
    #pragma unroll
    for (int i = 0; i < 64; i++) { mw[i] = MW[lane*64 + i]; mq[i] = MQ[lane*64 + i]; }
    float dw = dW[lane], dq = dQ[lane], wa = W_a[lane];
    int r = blockIdx.x * 4 + wv;
    if (r >= N_RELS) return;
    float e = relE[(size_t)r * 64 + lane];
    float w = dw, q = dq;
    #pragma unroll
    for (int i = 0; i < 64; i++) {
        float ei = __shfl(e, i, 64);
        w += ei * mw[i];
        q += ei * mq[i];
    }
    Wr[(size_t)r * 64 + lane] = w;
    Qr[(size_t)r * 64 + lane] = q;
    float tw = w * wa;
    #pragma unroll
    for (int o = 32; o; o >>= 1) tw += __shfl_xor(tw, o, 64);
    if (lane == 0) wsr[r] = tw;
}

__global__ void k_zero(int* __restrict__ a, int n) {
    int g = blockIdx.x * 256 + threadIdx.x;
    if (g < n) a[g] = 0;
}

// ---------------------------------------------------------------------------
// K3: histogram. Block-partitioned (SC_EDGES edges/block, same partition as
// k_scatter). src counts: direct fire-and-forget atomics (100k addrs, ~10-way).
// rel counts: LDS-aggregated; per-(block,rel) counts stored to blkhist so the
// scatter can be atomics-free on the rel side.
// ---------------------------------------------------------------------------
__global__ __launch_bounds__(256) void k_hist(const int* __restrict__ src, const int* __restrict__ rel,
        int* __restrict__ cnt_src, int* __restrict__ cnt_rel, int* __restrict__ blkhist) {
    __shared__ int lcnt[N_RELS];
    int t = threadIdx.x;
    for (int r = t; r < N_RELS; r += 256) lcnt[r] = 0;
    __syncthreads();
    int base = blockIdx.x * SC_EDGES;
    int end = min(base + SC_EDGES, N_EDGES);
    for (int g = base + t; g < end; g += 256) {
        atomicAdd(&cnt_src[src[g]], 1);
        atomicAdd(&lcnt[rel[g]], 1);
    }
    __syncthreads();
    for (int r = t; r < N_RELS; r += 256) {
        int c = lcnt[r];
        blkhist[blockIdx.x * N_RELS + r] = c;
        if (c) atomicAdd(&cnt_rel[r], c);
    }
}

// exclusive scan of cnt over chunks of 1024; partials[b] = chunk total
__global__ void k_scan_local(const int* __restrict__ cnt, int* __restrict__ start,
                             int* __restrict__ partials, int n) {
    __shared__ int tot[256];
    int base = blockIdx.x * 1024;
    int t = threadIdx.x;
    int myv[4];
    int mySum = 0;
    for (int q = 0; q < 4; q++) {
        int g = base + t * 4 + q;
        int v = (g < n) ? cnt[g] : 0;
        myv[q] = v; mySum += v;
    }
    tot[t] = mySum;
    __syncthreads();
    for (int o = 1; o < 256; o <<= 1) {
        int v = (t >= o) ? tot[t - o] : 0;
        __syncthreads();
        tot[t] += v;
        __syncthreads();
    }
    int run = tot[t] - mySum;
    for (int q = 0; q < 4; q++) {
        int g = base + t * 4 + q;
        if (g < n) start[g] = run;
        run += myv[q];
    }
    if (t == 255) partials[blockIdx.x] = tot[255];
}

// parallel in-place exclusive scan of partials (n <= 256), single block
__global__ void k_scan_part(int* __restrict__ partials, int n) {
    __shared__ int s[256];
    int t = threadIdx.x;
    int v = (t < n) ? partials[t] : 0;
    s[t] = v;
    __syncthreads();
    for (int o = 1; o < 256; o <<= 1) {
        int u = (t >= o) ? s[t - o] : 0;
        __syncthreads();
        s[t] += u;
        __syncthreads();
    }
    if (t < n) partials[t] = s[t] - v;
}

__global__ void k_scan_add(int* __restrict__ start, const int* __restrict__ partials,
                           int* __restrict__ ctr, int n) {
    int g = blockIdx.x * 256 + threadIdx.x;
    if (g < n) {
        int v = start[g] + partials[g >> 10];
        start[g] = v;
        ctr[g] = v;
    }
}

// single-block exclusive scan for n <= 1024 (rel counts)
__global__ void k_scan_small(const int* __restrict__ cnt, int* __restrict__ start, int n) {
    __shared__ int tot[256];
    int t = threadIdx.x;
    int myv[4];
    int mySum = 0;
    for (int q = 0; q < 4; q++) {
        int g = t * 4 + q;
        int v = (g < n) ? cnt[g] : 0;
        myv[q] = v; mySum += v;
    }
    tot[t] = mySum;
    __syncthreads();
    for (int o = 1; o < 256; o <<= 1) {
        int u = (t >= o) ? tot[t - o] : 0;
        __syncthreads();
        tot[t] += u;
        __syncthreads();
    }
    int run = tot[t] - mySum;
    for (int q = 0; q < 4; q++) {
        int g = t * 4 + q;
        if (g < n) start[g] = run;
        run += myv[q];
    }
}

// per-(block,rel) base = start_rel[r] + running sum of blkhist column r.
// lanes r..r+63 read contiguous ints at each b -> coalesced.
__global__ void k_scan_relblk(const int* __restrict__ start_rel, const int* __restrict__ blkhist,
                              int* __restrict__ blkbase) {
    int r = blockIdx.x * 256 + threadIdx.x;
    if (r >= N_RELS) return;
    int run = start_rel[r];
    for (int b = 0; b < NB_E; b++) {
        int v = blkhist[b * N_RELS + r];
        blkbase[b * N_RELS + r] = run;
        run += v;
    }
}

// ---------------------------------------------------------------------------
// K5: scatter. Writes payloads, not edge ids:
//   pay_src[p] = {dst, rel}   (src-sorted order)
//   pay_rel[q] = {src, dst}   (rel-sorted order)
// rel side uses precomputed per-block bases + LDS offsets (no global atomics);
// src side uses direct atomics (~10-way contention).
// ---------------------------------------------------------------------------
__global__ __launch_bounds__(256) void k_scatter(const int* __restrict__ src, const int* __restrict__ dst,
        const int* __restrict__ rel, int* __restrict__ ctr_src,
        const int* __restrict__ blkbase, int2* __restrict__ pay_src, int2* __restrict__ pay_rel) {
    __shared__ int lbase[N_RELS];
    __shared__ int loff[N_RELS];
    int t = threadIdx.x;
    for (int r = t; r < N_RELS; r += 256) { lbase[r] = blkbase[blockIdx.x * N_RELS + r]; loff[r] = 0; }
    __syncthreads();
    int base = blockIdx.x * SC_EDGES;
    int end = min(base + SC_EDGES, N_EDGES);
    for (int g = base + t; g < end; g += 256) {
        int s = src[g], d = dst[g], r = rel[g];
        int p = atomicAdd(&ctr_src[s], 1);
        pay_src[p] = make_int2(d, r);
        int q = lbase[r] + atomicAdd(&loff[r], 1);
        pay_rel[q] = make_int2(s, d);
    }
}

// ---------------------------------------------------------------------------
// K6: fused scatter-softmax + neighbor aggregation. Wave per source node.
// ---------------------------------------------------------------------------
__global__ __launch_bounds__(256) void k_attn(const int2* __restrict__ pay,
        const int* __restrict__ start_src, const int* __restrict__ cnt_src,
        const float* __restrict__ us, const float* __restrict__ vs,
        const float* __restrict__ wsr, const float* __restrict__ V,
        const float* __restrict__ Wr, const float* __restrict__ b_a_p,
        float* __restrict__ h) {
    int lane = threadIdx.x & 63;
    int wv = threadIdx.x >> 6;
    int n = blockIdx.x * 4 + wv;
    if (n >= N_NODES) return;
    int st = start_src[n];
    int cnt = cnt_src[n];
    if (cnt == 0) { h[(size_t)n * 64 + lane] = 0.f; return; }
    float ba = b_a_p[0];
    float usn = us[n];
    // pass 1: b_sum (lane-parallel over edges)
    float bp = 0.f;
    for (int k = lane; k < cnt; k += 64) {
        int2 p = pay[st + k];
        float s = usn + vs[p.x] + wsr[p.y] + ba;
        s = s > 0.f ? s : SLOPE * s;
        bp += expf(s);
    }
    #pragma unroll
    for (int o = 32; o; o >>= 1) bp += __shfl_xor(bp, o, 64);
    float inv = 1.f / bp;
    // pass 2: vector accumulation (lane = dim)
    float acc = 0.f;
    for (int k = 0; k < cnt; k++) {
        int2 p = pay[st + k];
        float s = usn + vs[p.x] + wsr[p.y] + ba;
        s = s > 0.f ? s : SLOPE * s;
        float b = expf(s);
        acc += b * (V[(size_t)p.x * 64 + lane] + Wr[(size_t)p.y * 64 + lane]);
    }
    float u = h[(size_t)n * 64 + lane];
    h[(size_t)n * 64 + lane] = u + acc * inv;
}

// ---------------------------------------------------------------------------
// K7: relation pooling partials from the {src,dst} payload.
// ---------------------------------------------------------------------------
__global__ __launch_bounds__(256) void k_relpool(const int2* __restrict__ pay,
        const int* __restrict__ start_rel, const int* __restrict__ cnt_rel,
        const float* __restrict__ h, float* __restrict__ acc_rel) {
    int r = blockIdx.x / RSUB;
    int sub = blockIdx.x % RSUB;
    int st = start_rel[r];
    int cnt = cnt_rel[r];
    int t = threadIdx.x;
    int half = t >> 7;
    int ld = t & 127;
    float a = 0.f;
    for (int k = half + 2 * sub; k < cnt; k += 2 * RSUB) {
        int2 p = pay[st + k];
        int idx = (ld < 64) ? p.x : p.y;
        a += h[(size_t)idx * 64 + (ld & 63)];
    }
    __shared__ float sums[256];
    sums[t] = a;
    __syncthreads();
    if (t < 128) atomicAdd(&acc_rel[r * 128 + t], sums[t] + sums[t + 128]);
}

// K8: mean + h_rel = mean @ W_rel3.T + b_rel3
__global__ void k_relfin(const float* __restrict__ acc_rel, const int* __restrict__ cnt_rel,
                         const float* __restrict__ Qr, const float* __restrict__ W_rel3,
                         const float* __restrict__ b_rel3, float* __restrict__ out) {
    int g = blockIdx.x * 256 + threadIdx.x;
    if (g >= N_RELS * 64) return;
    int r = g >> 6;
    int j = g & 63;
    int cnt = cnt_rel[r];
    float invc = 1.f / (float)(cnt > 0 ? cnt : 1);
    float s = b_rel3[j];
    for (int k = 0; k < 128; k++) s += acc_rel[r * 128 + k] * invc * W_rel3[j * 192 + k];
    if (cnt > 0)
        for (int k = 0; k < 64; k++) s += Qr[r * 64 + k] * W_rel3[j * 192 + 128 + k];
    out[g] = s;
}

extern "C" void kernel_launch(void* const* d_in, const int* in_sizes, int n_in,
                              void* d_out, int out_size, void* d_ws, size_t ws_size,
                              hipStream_t stream) {
    const float* ent    = (const float*)d_in[0];
    const float* relE   = (const float*)d_in[1];
    const float* W_ent  = (const float*)d_in[2];
    const float* b_ent  = (const float*)d_in[3];
    const float* W_relL = (const float*)d_in[4];
    const float* b_relL = (const float*)d_in[5];
    const float* W_rel2 = (const float*)d_in[6];
    const float* b_rel2 = (const float*)d_in[7];
    const float* W_rel3 = (const float*)d_in[8];
    const float* b_rel3 = (const float*)d_in[9];
    const float* W_a    = (const float*)d_in[10];
    const float* b_a    = (const float*)d_in[11];
    const float* W_fc   = (const float*)d_in[12];
    const float* b_fc   = (const float*)d_in[13];
    const int* src = (const int*)d_in[14];
    const int* dst = (const int*)d_in[15];
    const int* rel = (const int*)d_in[16];
    float* out = (float*)d_out;

    char* ws = (char*)d_ws;
    size_t off = 0;
    auto alloc = [&](size_t bytes) -> void* {
        void* p = ws + off;
        off += (bytes + 255) & ~(size_t)255;
        return p;
    };
    float* MU  = (float*)alloc(4096 * 4);
    float* MV  = (float*)alloc(4096 * 4);
    float* MW  = (float*)alloc(4096 * 4);
    float* MQ  = (float*)alloc(4096 * 4);
    float* dU  = (float*)alloc(64 * 4);
    float* dV  = (float*)alloc(64 * 4);
    float* dW  = (float*)alloc(64 * 4);
    float* dQ  = (float*)alloc(64 * 4);
    float* V   = (float*)alloc((size_t)N_NODES * 64 * 4);
    float* us  = (float*)alloc((size_t)N_NODES * 4);
    float* vs  = (float*)alloc((size_t)N_NODES * 4);
    float* Wr  = (float*)alloc((size_t)N_RELS * 64 * 4);
    float* Qr  = (float*)alloc((size_t)N_RELS * 64 * 4);
    float* wsr = (float*)alloc((size_t)N_RELS * 4);
    int* cnt_src   = (int*)alloc((size_t)N_NODES * 4);
    int* start_src = (int*)alloc((size_t)N_NODES * 4);
    int* ctr_src   = (int*)alloc((size_t)N_NODES * 4);
    int* partials  = (int*)alloc(256 * 4);
    int* cnt_rel   = (int*)alloc((size_t)N_RELS * 4);
    int* start_rel = (int*)alloc((size_t)N_RELS * 4);
    int* blkhist   = (int*)alloc((size_t)NB_E * N_RELS * 4);
    int* blkbase   = (int*)alloc((size_t)NB_E * N_RELS * 4);
    int2* pay_src  = (int2*)alloc((size_t)N_EDGES * 8);
    int2* pay_rel  = (int2*)alloc((size_t)N_EDGES * 8);
    float* acc_rel = (float*)alloc((size_t)N_RELS * 128 * 4);

    // zero the histogram / accumulator scratch (ws is poisoned 0xAA each call)
    k_zero<<<(N_NODES + 255) / 256, 256, 0, stream>>>(cnt_src, N_NODES);
    k_zero<<<(N_RELS + 255) / 256, 256, 0, stream>>>(cnt_rel, N_RELS);
    k_zero<<<(N_RELS * 128 + 255) / 256, 256, 0, stream>>>((int*)acc_rel, N_RELS * 128);

    k_fold<<<65, 256, 0, stream>>>(W_ent, b_ent, W_relL, b_relL, W_rel2, b_rel2,
                                   W_fc, b_fc, MU, MV, MW, MQ, dU, dV, dW, dQ);
    k_node<<<1024, 256, 0, stream>>>(ent, MU, MV, dU, dV, W_a, out, V, us, vs);
    k_relproj<<<125, 256, 0, stream>>>(relE, MW, MQ, dW, dQ, W_a, Wr, Qr, wsr);
    k_hist<<<NB_E, 256, 0, stream>>>(src, rel, cnt_src, cnt_rel, blkhist);
    k_scan_local<<<98, 256, 0, stream>>>(cnt_src, start_src, partials, N_NODES);
    k_scan_part<<<1, 256, 0, stream>>>(partials, 98);
    k_scan_add<<<(N_NODES + 255) / 256, 256, 0, stream>>>(start_src, partials, ctr_src, N_NODES);
    k_scan_small<<<1, 256, 0, stream>>>(cnt_rel, start_rel, N_RELS);
    k_scan_relblk<<<2, 256, 0, stream>>>(start_rel, blkhist, blkbase);
    k_scatter<<<NB_E, 256, 0, stream>>>(src, dst, rel, ctr_src, blkbase, pay_src, pay_rel);
    k_attn<<<N_NODES / 4, 256, 0, stream>>>(pay_src, start_src, cnt_src,
                                            us, vs, wsr, V, Wr, b_a, out);
    k_relpool<<<N_RELS * RSUB, 256, 0, stream>>>(pay_rel, start_rel, cnt_rel, out, acc_rel);
    k_relfin<<<(N_RELS * 64 + 255) / 256, 256, 0, stream>>>(acc_rel, cnt_rel, Qr, W_rel3,
                                                            b_rel3, out + (size_t)N_NODES * 64);
}

// Round 3
// 501.683 us; speedup vs baseline: 2.6772x; 1.3519x over previous
//
#include <hip/hip_runtime.h>
#include <math.h>

#define N_NODES 100000
#define N_RELS  500
#define DIM     64
#define N_EDGES 1000000
#define SLOPE   0.01f
#define RSUB    16      // blocks per relation in pooling
#define SC_EDGES 8192   // edges per block in hist/scatter partition
#define NB_E    123     // ceil(N_EDGES / SC_EDGES)

// ---------------------------------------------------------------------------
// K0: fold the small matrices.
// ---------------------------------------------------------------------------
__global__ void k_fold(const float* __restrict__ W_ent, const float* __restrict__ b_ent,
                       const float* __restrict__ W_relL, const float* __restrict__ b_relL,
                       const float* __restrict__ W_rel2, const float* __restrict__ b_rel2,
                       const float* __restrict__ W_fc, const float* __restrict__ b_fc,
                       float* __restrict__ MU, float* __restrict__ MV,
                       float* __restrict__ MW, float* __restrict__ MQ,
                       float* __restrict__ dU, float* __restrict__ dV,
                       float* __restrict__ dW, float* __restrict__ dQ) {
    int idx = blockIdx.x * 256 + threadIdx.x;
    if (idx < 4 * 4096) {
        int mat = idx >> 12;
        int rem = idx & 4095;
        int j = rem >> 6;
        int i = rem & 63;
        float s = 0.f;
        if (mat == 0) { for (int k = 0; k < 64; k++) s += W_fc[j*192 + k]       * W_ent[k*64 + i];  MU[j*64 + i] = s; }
        else if (mat == 1) { for (int k = 0; k < 64; k++) s += W_fc[j*192 + 64 + k]  * W_ent[k*64 + i];  MV[j*64 + i] = s; }
        else if (mat == 2) { for (int k = 0; k < 64; k++) s += W_fc[j*192 + 128 + k] * W_relL[k*64 + i]; MW[j*64 + i] = s; }
        else               { for (int k = 0; k < 64; k++) s += W_rel2[j*64 + k]      * W_relL[k*64 + i]; MQ[j*64 + i] = s; }
    } else if (idx < 4 * 4096 + 256) {
        int rem = idx - 4 * 4096;
        int vec = rem >> 6;
        int j = rem & 63;
        float s = 0.f;
        if (vec == 0)      { for (int k = 0; k < 64; k++) s += b_ent[k]  * W_fc[j*192 + k];       dU[j] = s; }
        else if (vec == 1) { for (int k = 0; k < 64; k++) s += b_ent[k]  * W_fc[j*192 + 64 + k];  dV[j] = s; }
        else if (vec == 2) { s = b_fc[j];   for (int k = 0; k < 64; k++) s += b_relL[k] * W_fc[j*192 + 128 + k]; dW[j] = s; }
        else               { s = b_rel2[j]; for (int k = 0; k < 64; k++) s += b_relL[k] * W_rel2[j*64 + k];      dQ[j] = s; }
    }
}

// ---------------------------------------------------------------------------
// K1: per-node projections (wave per node, weights in VGPRs).
// ---------------------------------------------------------------------------
__global__ __launch_bounds__(256, 2) void k_node(const float* __restrict__ ent,
        const float* __restrict__ MU, const float* __restrict__ MV,
        const float* __restrict__ dU, const float* __restrict__ dV,
        const float* __restrict__ W_a,
        float* __restrict__ Uout, float* __restrict__ V,
        float* __restrict__ us, float* __restrict__ vs) {
    int lane = threadIdx.x & 63;
    int wv = threadIdx.x >> 6;
    float mu[64], mv[64];
    #pragma unroll
    for (int i = 0; i < 64; i++) { mu[i] = MU[lane*64 + i]; mv[i] = MV[lane*64 + i]; }
    float du = dU[lane], dv = dV[lane], wa = W_a[lane];
    for (int n = blockIdx.x * 4 + wv; n < N_NODES; n += gridDim.x * 4) {
        float e = ent[(size_t)n * 64 + lane];
        float u = du, v = dv;
        #pragma unroll
        for (int i = 0; i < 64; i++) {
            float ei = __shfl(e, i, 64);
            u += ei * mu[i];
            v += ei * mv[i];
        }
        Uout[(size_t)n * 64 + lane] = u;
        V[(size_t)n * 64 + lane] = v;
        float tu = u * wa, tv = v * wa;
        #pragma unroll
        for (int o = 32; o; o >>= 1) { tu += __shfl_xor(tu, o, 64); tv += __shfl_xor(tv, o, 64); }
        if (lane == 0) { us[n] = tu; vs[n] = tv; }
    }
}

// K2: per-relation projections.
__global__ __launch_bounds__(256, 2) void k_relproj(const float* __restrict__ relE,
        const float* __restrict__ MW, const float* __restrict__ MQ,
        const float* __restrict__ dW, const float* __restrict__ dQ,
        const float* __restrict__ W_a,
        float* __restrict__ Wr, float* __restrict__ Qr, float* __restrict__ wsr) {
    int lane = threadIdx.x & 63;
    int wv = threadIdx.x >> 6;
    float mw[64], mq[64];
    #pragma unroll
    for (int i = 0; i < 64; i++) { mw[i] = MW[lane*64 + i]; mq[i] = MQ[lane*64 + i]; }
    float dw = dW[lane], dq = dQ[lane], wa = W_a[lane];
    int r = blockIdx.x * 4 + wv;
    if (r >= N_RELS) return;
    float e = relE[(size_t)r * 64 + lane];
    float w = dw, q = dq;
    #pragma unroll
    for (int i = 0; i < 64; i++) {
        float ei = __shfl(e, i, 64);
        w += ei * mw[i];
        q += ei * mq[i];
    }
    Wr[(size_t)r * 64 + lane] = w;
    Qr[(size_t)r * 64 + lane] = q;
    float tw = w * wa;
    #pragma unroll
    for (int o = 32; o; o >>= 1) tw += __shfl_xor(tw, o, 64);
    if (lane == 0) wsr[r] = tw;
}

__global__ void k_zero(int* __restrict__ a, int n) {
    int g = blockIdx.x * 256 + threadIdx.x;
    if (g < n) a[g] = 0;
}

// ---------------------------------------------------------------------------
// K3: histogram (block-partitioned; rel via LDS + blkhist, src via atomics).
// ---------------------------------------------------------------------------
__global__ __launch_bounds__(256) void k_hist(const int* __restrict__ src, const int* __restrict__ rel,
        int* __restrict__ cnt_src, int* __restrict__ cnt_rel, int* __restrict__ blkhist) {
    __shared__ int lcnt[N_RELS];
    int t = threadIdx.x;
    for (int r = t; r < N_RELS; r += 256) lcnt[r] = 0;
    __syncthreads();
    int base = blockIdx.x * SC_EDGES;
    int end = min(base + SC_EDGES, N_EDGES);
    for (int g = base + t; g < end; g += 256) {
        atomicAdd(&cnt_src[src[g]], 1);
        atomicAdd(&lcnt[rel[g]], 1);
    }
    __syncthreads();
    for (int r = t; r < N_RELS; r += 256) {
        int c = lcnt[r];
        blkhist[blockIdx.x * N_RELS + r] = c;
        if (c) atomicAdd(&cnt_rel[r], c);
    }
}

// exclusive scan of cnt over chunks of 1024; partials[b] = chunk total
__global__ void k_scan_local(const int* __restrict__ cnt, int* __restrict__ start,
                             int* __restrict__ partials, int n) {
    __shared__ int tot[256];
    int base = blockIdx.x * 1024;
    int t = threadIdx.x;
    int myv[4];
    int mySum = 0;
    for (int q = 0; q < 4; q++) {
        int g = base + t * 4 + q;
        int v = (g < n) ? cnt[g] : 0;
        myv[q] = v; mySum += v;
    }
    tot[t] = mySum;
    __syncthreads();
    for (int o = 1; o < 256; o <<= 1) {
        int v = (t >= o) ? tot[t - o] : 0;
        __syncthreads();
        tot[t] += v;
        __syncthreads();
    }
    int run = tot[t] - mySum;
    for (int q = 0; q < 4; q++) {
        int g = base + t * 4 + q;
        if (g < n) start[g] = run;
        run += myv[q];
    }
    if (t == 255) partials[blockIdx.x] = tot[255];
}

__global__ void k_scan_part(int* __restrict__ partials, int n) {
    __shared__ int s[256];
    int t = threadIdx.x;
    int v = (t < n) ? partials[t] : 0;
    s[t] = v;
    __syncthreads();
    for (int o = 1; o < 256; o <<= 1) {
        int u = (t >= o) ? s[t - o] : 0;
        __syncthreads();
        s[t] += u;
        __syncthreads();
    }
    if (t < n) partials[t] = s[t] - v;
}

__global__ void k_scan_add(int* __restrict__ start, const int* __restrict__ partials,
                           int* __restrict__ ctr, int n) {
    int g = blockIdx.x * 256 + threadIdx.x;
    if (g < n) {
        int v = start[g] + partials[g >> 10];
        start[g] = v;
        ctr[g] = v;
    }
}

__global__ void k_scan_small(const int* __restrict__ cnt, int* __restrict__ start, int n) {
    __shared__ int tot[256];
    int t = threadIdx.x;
    int myv[4];
    int mySum = 0;
    for (int q = 0; q < 4; q++) {
        int g = t * 4 + q;
        int v = (g < n) ? cnt[g] : 0;
        myv[q] = v; mySum += v;
    }
    tot[t] = mySum;
    __syncthreads();
    for (int o = 1; o < 256; o <<= 1) {
        int u = (t >= o) ? tot[t - o] : 0;
        __syncthreads();
        tot[t] += u;
        __syncthreads();
    }
    int run = tot[t] - mySum;
    for (int q = 0; q < 4; q++) {
        int g = t * 4 + q;
        if (g < n) start[g] = run;
        run += myv[q];
    }
}

__global__ void k_scan_relblk(const int* __restrict__ start_rel, const int* __restrict__ blkhist,
                              int* __restrict__ blkbase) {
    int r = blockIdx.x * 256 + threadIdx.x;
    if (r >= N_RELS) return;
    int run = start_rel[r];
    for (int b = 0; b < NB_E; b++) {
        int v = blkhist[b * N_RELS + r];
        blkbase[b * N_RELS + r] = run;
        run += v;
    }
}

// ---------------------------------------------------------------------------
// K5: scatter payloads. pay_src[p]={dst,rel} (src-sorted); pay_rel[q]={src,dst}
// (rel-sorted, no global atomics via per-block bases).
// ---------------------------------------------------------------------------
__global__ __launch_bounds__(256) void k_scatter(const int* __restrict__ src, const int* __restrict__ dst,
        const int* __restrict__ rel, int* __restrict__ ctr_src,
        const int* __restrict__ blkbase, int2* __restrict__ pay_src, int2* __restrict__ pay_rel) {
    __shared__ int lbase[N_RELS];
    __shared__ int loff[N_RELS];
    int t = threadIdx.x;
    for (int r = t; r < N_RELS; r += 256) { lbase[r] = blkbase[blockIdx.x * N_RELS + r]; loff[r] = 0; }
    __syncthreads();
    int base = blockIdx.x * SC_EDGES;
    int end = min(base + SC_EDGES, N_EDGES);
    for (int g = base + t; g < end; g += 256) {
        int s = src[g], d = dst[g], r = rel[g];
        int p = atomicAdd(&ctr_src[s], 1);
        pay_src[p] = make_int2(d, r);
        int q = lbase[r] + atomicAdd(&loff[r], 1);
        pay_rel[q] = make_int2(s, d);
    }
}

// ---------------------------------------------------------------------------
// K6: fused scatter-softmax + neighbor aggregation. Wave per source node.
// Fast path (cnt<=64): lane l caches edge l's payload+exp in registers;
// pass 2 gathers 4 V/Wr rows per iteration via float4 (16 lanes/row).
// ---------------------------------------------------------------------------
__global__ __launch_bounds__(256) void k_attn(const int2* __restrict__ pay,
        const int* __restrict__ start_src, const int* __restrict__ cnt_src,
        const float* __restrict__ us, const float* __restrict__ vs,
        const float* __restrict__ wsr, const float* __restrict__ V,
        const float* __restrict__ Wr, const float* __restrict__ b_a_p,
        float* __restrict__ h) {
    int lane = threadIdx.x & 63;
    int wv = threadIdx.x >> 6;
    int n = blockIdx.x * 4 + wv;
    if (n >= N_NODES) return;
    int st = start_src[n];
    int cnt = cnt_src[n];
    if (cnt == 0) { h[(size_t)n * 64 + lane] = 0.f; return; }
    float ba = b_a_p[0];
    float usn = us[n];

    if (cnt <= 64) {
        int2 pe = (lane < cnt) ? pay[st + lane] : make_int2(0, 0);
        float bexp = 0.f;
        if (lane < cnt) {
            float s = usn + vs[pe.x] + wsr[pe.y] + ba;
            s = s > 0.f ? s : SLOPE * s;
            bexp = expf(s);
        }
        float bp = bexp;
        #pragma unroll
        for (int o = 32; o; o >>= 1) bp += __shfl_xor(bp, o, 64);
        float inv = 1.f / bp;
        int sub = lane >> 4;   // which edge within the 4-edge group
        int li = lane & 15;    // float4 slot within row
        float4 acc = make_float4(0.f, 0.f, 0.f, 0.f);
        int groups = (cnt + 3) >> 2;
        for (int g = 0; g < groups; g++) {
            int esel = 4 * g + sub;          // < 64 always
            float be = __shfl(bexp, esel, 64);
            int de = __shfl(pe.x, esel, 64);
            int re = __shfl(pe.y, esel, 64);
            float4 vv = *(const float4*)(V + (size_t)de * 64 + li * 4);
            float4 wvv = *(const float4*)(Wr + (size_t)re * 64 + li * 4);
            acc.x += be * (vv.x + wvv.x);
            acc.y += be * (vv.y + wvv.y);
            acc.z += be * (vv.z + wvv.z);
            acc.w += be * (vv.w + wvv.w);
        }
        // reduce over the 4 sub-edge groups (lanes l, l^16, l^32, l^48)
        acc.x += __shfl_xor(acc.x, 16, 64); acc.x += __shfl_xor(acc.x, 32, 64);
        acc.y += __shfl_xor(acc.y, 16, 64); acc.y += __shfl_xor(acc.y, 32, 64);
        acc.z += __shfl_xor(acc.z, 16, 64); acc.z += __shfl_xor(acc.z, 32, 64);
        acc.w += __shfl_xor(acc.w, 16, 64); acc.w += __shfl_xor(acc.w, 32, 64);
        if (lane < 16) {
            float4 u = *(const float4*)(h + (size_t)n * 64 + lane * 4);
            float4 o4;
            o4.x = u.x + acc.x * inv;
            o4.y = u.y + acc.y * inv;
            o4.z = u.z + acc.z * inv;
            o4.w = u.w + acc.w * inv;
            *(float4*)(h + (size_t)n * 64 + lane * 4) = o4;
        }
        return;
    }

    // fallback: scalar two-pass (cnt > 64)
    float bp = 0.f;
    for (int k = lane; k < cnt; k += 64) {
        int2 p = pay[st + k];
        float s = usn + vs[p.x] + wsr[p.y] + ba;
        s = s > 0.f ? s : SLOPE * s;
        bp += expf(s);
    }
    #pragma unroll
    for (int o = 32; o; o >>= 1) bp += __shfl_xor(bp, o, 64);
    float inv = 1.f / bp;
    float acc = 0.f;
    for (int k = 0; k < cnt; k++) {
        int2 p = pay[st + k];
        float s = usn + vs[p.x] + wsr[p.y] + ba;
        s = s > 0.f ? s : SLOPE * s;
        float b = expf(s);
        acc += b * (V[(size_t)p.x * 64 + lane] + Wr[(size_t)p.y * 64 + lane]);
    }
    float u = h[(size_t)n * 64 + lane];
    h[(size_t)n * 64 + lane] = u + acc * inv;
}

// ---------------------------------------------------------------------------
// K7: relation pooling. float4 gathers (16 rows / block-iteration = 8 edges),
// software-pipelined pay prefetch, contiguous chunks, LDS tree reduce.
// ---------------------------------------------------------------------------
__global__ __launch_bounds__(256) void k_relpool(const int2* __restrict__ pay,
        const int* __restrict__ start_rel, const int* __restrict__ cnt_rel,
        const float* __restrict__ h, float* __restrict__ acc_rel) {
    int r = blockIdx.x / RSUB;
    int sub = blockIdx.x % RSUB;
    int st = start_rel[r];
    int cnt = cnt_rel[r];
    int t = threadIdx.x;
    int j = t >> 5;          // 0..7: edge slot within iteration
    int side = (t >> 4) & 1; // 0=src, 1=dst
    int li = t & 15;         // float4 slot within row

    int chunk = (cnt + RSUB - 1) / RSUB;
    int k0 = sub * chunk;
    int k1 = min(k0 + chunk, cnt);
    int len = k1 - k0;

    float4 acc = make_float4(0.f, 0.f, 0.f, 0.f);
    if (len > 0) {
        int steps = (len + 7) >> 3;
        int k = k0 + j;
        bool v = (j < len);
        int2 p = v ? pay[st + k] : make_int2(0, 0);
        for (int it = 0; it < steps; it++) {
            k += 8;
            bool vn = (it + 1 < steps) && (k < k1);
            int2 pn = vn ? pay[st + k] : make_int2(0, 0);
            int idx = side ? p.y : p.x;
            float4 hv = *(const float4*)(h + (size_t)idx * 64 + li * 4);
            if (v) {
                acc.x += hv.x; acc.y += hv.y; acc.z += hv.z; acc.w += hv.w;
            }
            p = pn; v = vn;
        }
    }
    __shared__ float4 red[256];
    red[t] = acc;
    __syncthreads();
    if (t < 128) {
        float4 a = red[t], b = red[t + 128];
        a.x += b.x; a.y += b.y; a.z += b.z; a.w += b.w;
        red[t] = a;
    }
    __syncthreads();
    if (t < 64) {
        float4 a = red[t], b = red[t + 64];
        a.x += b.x; a.y += b.y; a.z += b.z; a.w += b.w;
        red[t] = a;
    }
    __syncthreads();
    if (t < 32) {
        float4 a = red[t], b = red[t + 32];
        a.x += b.x; a.y += b.y; a.z += b.z; a.w += b.w;
        float* dstp = &acc_rel[r * 128 + side * 64 + li * 4];
        atomicAdd(dstp + 0, a.x);
        atomicAdd(dstp + 1, a.y);
        atomicAdd(dstp + 2, a.z);
        atomicAdd(dstp + 3, a.w);
    }
}

// K8: mean + h_rel = mean @ W_rel3.T + b_rel3
__global__ void k_relfin(const float* __restrict__ acc_rel, const int* __restrict__ cnt_rel,
                         const float* __restrict__ Qr, const float* __restrict__ W_rel3,
                         const float* __restrict__ b_rel3, float* __restrict__ out) {
    int g = blockIdx.x * 256 + threadIdx.x;
    if (g >= N_RELS * 64) return;
    int r = g >> 6;
    int j = g & 63;
    int cnt = cnt_rel[r];
    float invc = 1.f / (float)(cnt > 0 ? cnt : 1);
    float s = b_rel3[j];
    for (int k = 0; k < 128; k++) s += acc_rel[r * 128 + k] * invc * W_rel3[j * 192 + k];
    if (cnt > 0)
        for (int k = 0; k < 64; k++) s += Qr[r * 64 + k] * W_rel3[j * 192 + 128 + k];
    out[g] = s;
}

extern "C" void kernel_launch(void* const* d_in, const int* in_sizes, int n_in,
                              void* d_out, int out_size, void* d_ws, size_t ws_size,
                              hipStream_t stream) {
    const float* ent    = (const float*)d_in[0];
    const float* relE   = (const float*)d_in[1];
    const float* W_ent  = (const float*)d_in[2];
    const float* b_ent  = (const float*)d_in[3];
    const float* W_relL = (const float*)d_in[4];
    const float* b_relL = (const float*)d_in[5];
    const float* W_rel2 = (const float*)d_in[6];
    const float* b_rel2 = (const float*)d_in[7];
    const float* W_rel3 = (const float*)d_in[8];
    const float* b_rel3 = (const float*)d_in[9];
    const float* W_a    = (const float*)d_in[10];
    const float* b_a    = (const float*)d_in[11];
    const float* W_fc   = (const float*)d_in[12];
    const float* b_fc   = (const float*)d_in[13];
    const int* src = (const int*)d_in[14];
    const int* dst = (const int*)d_in[15];
    const int* rel = (const int*)d_in[16];
    float* out = (float*)d_out;

    char* ws = (char*)d_ws;
    size_t off = 0;
    auto alloc = [&](size_t bytes) -> void* {
        void* p = ws + off;
        off += (bytes + 255) & ~(size_t)255;
        return p;
    };
    float* MU  = (float*)alloc(4096 * 4);
    float* MV  = (float*)alloc(4096 * 4);
    float* MW  = (float*)alloc(4096 * 4);
    float* MQ  = (float*)alloc(4096 * 4);
    float* dU  = (float*)alloc(64 * 4);
    float* dV  = (float*)alloc(64 * 4);
    float* dW  = (float*)alloc(64 * 4);
    float* dQ  = (float*)alloc(64 * 4);
    float* V   = (float*)alloc((size_t)N_NODES * 64 * 4);
    float* us  = (float*)alloc((size_t)N_NODES * 4);
    float* vs  = (float*)alloc((size_t)N_NODES * 4);
    float* Wr  = (float*)alloc((size_t)N_RELS * 64 * 4);
    float* Qr  = (float*)alloc((size_t)N_RELS * 64 * 4);
    float* wsr = (float*)alloc((size_t)N_RELS * 4);
    int* cnt_src   = (int*)alloc((size_t)N_NODES * 4);
    int* start_src = (int*)alloc((size_t)N_NODES * 4);
    int* ctr_src   = (int*)alloc((size_t)N_NODES * 4);
    int* partials  = (int*)alloc(256 * 4);
    int* cnt_rel   = (int*)alloc((size_t)N_RELS * 4);
    int* start_rel = (int*)alloc((size_t)N_RELS * 4);
    int* blkhist   = (int*)alloc((size_t)NB_E * N_RELS * 4);
    int* blkbase   = (int*)alloc((size_t)NB_E * N_RELS * 4);
    int2* pay_src  = (int2*)alloc((size_t)N_EDGES * 8);
    int2* pay_rel  = (int2*)alloc((size_t)N_EDGES * 8);
    float* acc_rel = (float*)alloc((size_t)N_RELS * 128 * 4);

    k_zero<<<(N_NODES + 255) / 256, 256, 0, stream>>>(cnt_src, N_NODES);
    k_zero<<<(N_RELS + 255) / 256, 256, 0, stream>>>(cnt_rel, N_RELS);
    k_zero<<<(N_RELS * 128 + 255) / 256, 256, 0, stream>>>((int*)acc_rel, N_RELS * 128);

    k_fold<<<65, 256, 0, stream>>>(W_ent, b_ent, W_relL, b_relL, W_rel2, b_rel2,
                                   W_fc, b_fc, MU, MV, MW, MQ, dU, dV, dW, dQ);
    k_node<<<1024, 256, 0, stream>>>(ent, MU, MV, dU, dV, W_a, out, V, us, vs);
    k_relproj<<<125, 256, 0, stream>>>(relE, MW, MQ, dW, dQ, W_a, Wr, Qr, wsr);
    k_hist<<<NB_E, 256, 0, stream>>>(src, rel, cnt_src, cnt_rel, blkhist);
    k_scan_local<<<98, 256, 0, stream>>>(cnt_src, start_src, partials, N_NODES);
    k_scan_part<<<1, 256, 0, stream>>>(partials, 98);
    k_scan_add<<<(N_NODES + 255) / 256, 256, 0, stream>>>(start_src, partials, ctr_src, N_NODES);
    k_scan_small<<<1, 256, 0, stream>>>(cnt_rel, start_rel, N_RELS);
    k_scan_relblk<<<2, 256, 0, stream>>>(start_rel, blkhist, blkbase);
    k_scatter<<<NB_E, 256, 0, stream>>>(src, dst, rel, ctr_src, blkbase, pay_src, pay_rel);
    k_attn<<<N_NODES / 4, 256, 0, stream>>>(pay_src, start_src, cnt_src,
                                            us, vs, wsr, V, Wr, b_a, out);
    k_relpool<<<N_RELS * RSUB, 256, 0, stream>>>(pay_rel, start_rel, cnt_rel, out, acc_rel);
    k_relfin<<<(N_RELS * 64 + 255) / 256, 256, 0, stream>>>(acc_rel, cnt_rel, Qr, W_rel3,
                                                            b_rel3, out + (size_t)N_NODES * 64);
}

// Round 4
// 411.622 us; speedup vs baseline: 3.2629x; 1.2188x over previous
//
#include <hip/hip_runtime.h>
#include <math.h>

#define N_NODES 100000
#define N_RELS  500
#define DIM     64
#define N_EDGES 1000000
#define SLOPE   0.01f
#define RSUB    16      // blocks per relation in pooling
#define SC_EDGES 8192   // edges per block in hist/scatter partition
#define NB_E    123     // ceil(N_EDGES / SC_EDGES)

// ---------------------------------------------------------------------------
// K0: fold the small matrices.
//  Wcat[k*128 + j], j<64:  MU[j][k] = sum_i W_fc[j,i]     * W_ent[i,k]
//                  j>=64:  MV[j'][k] = sum_i W_fc[j',64+i] * W_ent[i,k]
//  dcat[j] = b_ent @ corresponding W_fc block
//  MW/MQ/dW/dQ as before (used by k_relproj).
// ---------------------------------------------------------------------------
__global__ void k_fold(const float* __restrict__ W_ent, const float* __restrict__ b_ent,
                       const float* __restrict__ W_relL, const float* __restrict__ b_relL,
                       const float* __restrict__ W_rel2, const float* __restrict__ b_rel2,
                       const float* __restrict__ W_fc, const float* __restrict__ b_fc,
                       float* __restrict__ Wcat, float* __restrict__ dcat,
                       float* __restrict__ MW, float* __restrict__ MQ,
                       float* __restrict__ dW, float* __restrict__ dQ) {
    int idx = blockIdx.x * 256 + threadIdx.x;
    if (idx < 8192) {
        int k = idx >> 7;
        int j2 = idx & 127;
        int jj = j2 & 63;
        int off = (j2 >> 6) * 64;
        float s = 0.f;
        for (int i = 0; i < 64; i++) s += W_fc[jj*192 + off + i] * W_ent[i*64 + k];
        Wcat[k*128 + j2] = s;
    } else if (idx < 12288) {
        int rem = idx - 8192;
        int j = rem >> 6, i = rem & 63;
        float s = 0.f;
        for (int k = 0; k < 64; k++) s += W_fc[j*192 + 128 + k] * W_relL[k*64 + i];
        MW[j*64 + i] = s;
    } else if (idx < 16384) {
        int rem = idx - 12288;
        int j = rem >> 6, i = rem & 63;
        float s = 0.f;
        for (int k = 0; k < 64; k++) s += W_rel2[j*64 + k] * W_relL[k*64 + i];
        MQ[j*64 + i] = s;
    } else if (idx < 16512) {
        int j2 = idx - 16384;
        int jj = j2 & 63;
        int off = (j2 >> 6) * 64;
        float s = 0.f;
        for (int i = 0; i < 64; i++) s += b_ent[i] * W_fc[jj*192 + off + i];
        dcat[j2] = s;
    } else if (idx < 16640) {
        int rem = idx - 16512;
        int vec = rem >> 6, j = rem & 63;
        if (vec == 0) {
            float s = b_fc[j];
            for (int k = 0; k < 64; k++) s += b_relL[k] * W_fc[j*192 + 128 + k];
            dW[j] = s;
        } else {
            float s = b_rel2[j];
            for (int k = 0; k < 64; k++) s += b_relL[k] * W_rel2[j*64 + k];
            dQ[j] = s;
        }
    }
}

// ---------------------------------------------------------------------------
// K1: per-node projections as LDS-tiled register-blocked GEMM.
// Block = 64-node tile. Thread = 4 nodes x 8 outputs (of 128 = U||V).
// Per k: 4 broadcast LDS scalars + 2 ds_read_b128 of Wcat row -> 32 FMA.
// us/vs from the register tile via shfl_xor over the 8 j-groups per half.
// ---------------------------------------------------------------------------
__global__ __launch_bounds__(256) void k_node(const float* __restrict__ ent,
        const float* __restrict__ Wcat, const float* __restrict__ dcat,
        const float* __restrict__ W_a,
        float* __restrict__ Uout, float* __restrict__ V,
        float* __restrict__ us, float* __restrict__ vs) {
    __shared__ float sA[64][68];
    __shared__ float sW[64][128];
    int t = threadIdx.x;
    int tile0 = blockIdx.x * 64;
    // stage Wcat (8192 floats = 2048 float4)
    for (int i = t; i < 2048; i += 256)
        ((float4*)sW)[i] = ((const float4*)Wcat)[i];
    // stage ent tile (coalesced float4 reads)
    for (int f = t; f < 1024; f += 256) {
        int n = f >> 4, k4 = f & 15;
        float4 v4 = (tile0 + n < N_NODES)
            ? ((const float4*)(ent + (size_t)(tile0 + n) * 64))[k4]
            : make_float4(0.f, 0.f, 0.f, 0.f);
        *(float4*)&sA[n][k4 * 4] = v4;
    }
    __syncthreads();

    int ng = t >> 4;        // 0..15 node group
    int jg = t & 15;        // 0..15 output group (0..7 = U, 8..15 = V)
    int n0 = ng * 4;
    int j0 = jg * 8;

    float4 d0 = *(const float4*)(dcat + j0);
    float4 d1 = *(const float4*)(dcat + j0 + 4);
    float acc[4][8];
    #pragma unroll
    for (int a = 0; a < 4; a++) {
        acc[a][0] = d0.x; acc[a][1] = d0.y; acc[a][2] = d0.z; acc[a][3] = d0.w;
        acc[a][4] = d1.x; acc[a][5] = d1.y; acc[a][6] = d1.z; acc[a][7] = d1.w;
    }

    #pragma unroll 4
    for (int k = 0; k < 64; k++) {
        float4 w0 = *(const float4*)&sW[k][j0];
        float4 w1 = *(const float4*)&sW[k][j0 + 4];
        float e0 = sA[n0][k], e1 = sA[n0+1][k], e2 = sA[n0+2][k], e3 = sA[n0+3][k];
        float e[4] = {e0, e1, e2, e3};
        #pragma unroll
        for (int a = 0; a < 4; a++) {
            acc[a][0] += e[a] * w0.x; acc[a][1] += e[a] * w0.y;
            acc[a][2] += e[a] * w0.z; acc[a][3] += e[a] * w0.w;
            acc[a][4] += e[a] * w1.x; acc[a][5] += e[a] * w1.y;
            acc[a][6] += e[a] * w1.z; acc[a][7] += e[a] * w1.w;
        }
    }

    // ---- us / vs partial dot with W_a ----
    int jw = j0 & 63;
    float4 wa0 = *(const float4*)(W_a + jw);
    float4 wa1 = *(const float4*)(W_a + jw + 4);
    float part[4];
    #pragma unroll
    for (int a = 0; a < 4; a++) {
        part[a] = acc[a][0]*wa0.x + acc[a][1]*wa0.y + acc[a][2]*wa0.z + acc[a][3]*wa0.w
                + acc[a][4]*wa1.x + acc[a][5]*wa1.y + acc[a][6]*wa1.z + acc[a][7]*wa1.w;
    }
    #pragma unroll
    for (int m = 1; m <= 4; m <<= 1) {
        #pragma unroll
        for (int a = 0; a < 4; a++) part[a] += __shfl_xor(part[a], m, 64);
    }
    if ((jg & 7) == 0) {
        float* sv = (jg < 8) ? us : vs;
        #pragma unroll
        for (int a = 0; a < 4; a++)
            if (tile0 + n0 + a < N_NODES) sv[tile0 + n0 + a] = part[a];
    }

    // ---- store U / V ----
    #pragma unroll
    for (int a = 0; a < 4; a++) {
        int n = tile0 + n0 + a;
        if (n >= N_NODES) break;
        float4 o0 = make_float4(acc[a][0], acc[a][1], acc[a][2], acc[a][3]);
        float4 o1 = make_float4(acc[a][4], acc[a][5], acc[a][6], acc[a][7]);
        float* base = (jg < 8) ? (Uout + (size_t)n * 64 + j0) : (V + (size_t)n * 64 + (j0 - 64));
        *(float4*)(base) = o0;
        *(float4*)(base + 4) = o1;
    }
}

// K2: per-relation projections (unchanged, shfl-GEMM is fine at 500 rows).
__global__ __launch_bounds__(256, 2) void k_relproj(const float* __restrict__ relE,
        const float* __restrict__ MW, const float* __restrict__ MQ,
        const float* __restrict__ dW, const float* __restrict__ dQ,
        const float* __restrict__ W_a,
        float* __restrict__ Wr, float* __restrict__ Qr, float* __restrict__ wsr) {
    int lane = threadIdx.x & 63;
    int wv = threadIdx.x >> 6;
    float mw[64], mq[64];
    #pragma unroll
    for (int i = 0; i < 64; i++) { mw[i] = MW[lane*64 + i]; mq[i] = MQ[lane*64 + i]; }
    float dw = dW[lane], dq = dQ[lane], wa = W_a[lane];
    int r = blockIdx.x * 4 + wv;
    if (r >= N_RELS) return;
    float e = relE[(size_t)r * 64 + lane];
    float w = dw, q = dq;
    #pragma unroll
    for (int i = 0; i < 64; i++) {
        float ei = __shfl(e, i, 64);
        w += ei * mw[i];
        q += ei * mq[i];
    }
    Wr[(size_t)r * 64 + lane] = w;
    Qr[(size_t)r * 64 + lane] = q;
    float tw = w * wa;
    #pragma unroll
    for (int o = 32; o; o >>= 1) tw += __shfl_xor(tw, o, 64);
    if (lane == 0) wsr[r] = tw;
}

__global__ void k_zero(int* __restrict__ a, int n) {
    int g = blockIdx.x * 256 + threadIdx.x;
    if (g < n) a[g] = 0;
}

// ---------------------------------------------------------------------------
// K3: histogram (block-partitioned; rel via LDS + blkhist, src via atomics).
// ---------------------------------------------------------------------------
__global__ __launch_bounds__(256) void k_hist(const int* __restrict__ src, const int* __restrict__ rel,
        int* __restrict__ cnt_src, int* __restrict__ cnt_rel, int* __restrict__ blkhist) {
    __shared__ int lcnt[N_RELS];
    int t = threadIdx.x;
    for (int r = t; r < N_RELS; r += 256) lcnt[r] = 0;
    __syncthreads();
    int base = blockIdx.x * SC_EDGES;
    int end = min(base + SC_EDGES, N_EDGES);
    for (int g = base + t; g < end; g += 256) {
        atomicAdd(&cnt_src[src[g]], 1);
        atomicAdd(&lcnt[rel[g]], 1);
    }
    __syncthreads();
    for (int r = t; r < N_RELS; r += 256) {
        int c = lcnt[r];
        blkhist[blockIdx.x * N_RELS + r] = c;
        if (c) atomicAdd(&cnt_rel[r], c);
    }
}

// exclusive scan of cnt over chunks of 1024; partials[b] = chunk total
__global__ void k_scan_local(const int* __restrict__ cnt, int* __restrict__ start,
                             int* __restrict__ partials, int n) {
    __shared__ int tot[256];
    int base = blockIdx.x * 1024;
    int t = threadIdx.x;
    int myv[4];
    int mySum = 0;
    for (int q = 0; q < 4; q++) {
        int g = base + t * 4 + q;
        int v = (g < n) ? cnt[g] : 0;
        myv[q] = v; mySum += v;
    }
    tot[t] = mySum;
    __syncthreads();
    for (int o = 1; o < 256; o <<= 1) {
        int v = (t >= o) ? tot[t - o] : 0;
        __syncthreads();
        tot[t] += v;
        __syncthreads();
    }
    int run = tot[t] - mySum;
    for (int q = 0; q < 4; q++) {
        int g = base + t * 4 + q;
        if (g < n) start[g] = run;
        run += myv[q];
    }
    if (t == 255) partials[blockIdx.x] = tot[255];
}

__global__ void k_scan_part(int* __restrict__ partials, int n) {
    __shared__ int s[256];
    int t = threadIdx.x;
    int v = (t < n) ? partials[t] : 0;
    s[t] = v;
    __syncthreads();
    for (int o = 1; o < 256; o <<= 1) {
        int u = (t >= o) ? s[t - o] : 0;
        __syncthreads();
        s[t] += u;
        __syncthreads();
    }
    if (t < n) partials[t] = s[t] - v;
}

__global__ void k_scan_add(int* __restrict__ start, const int* __restrict__ partials,
                           int* __restrict__ ctr, int n) {
    int g = blockIdx.x * 256 + threadIdx.x;
    if (g < n) {
        int v = start[g] + partials[g >> 10];
        start[g] = v;
        ctr[g] = v;
    }
}

__global__ void k_scan_small(const int* __restrict__ cnt, int* __restrict__ start, int n) {
    __shared__ int tot[256];
    int t = threadIdx.x;
    int myv[4];
    int mySum = 0;
    for (int q = 0; q < 4; q++) {
        int g = t * 4 + q;
        int v = (g < n) ? cnt[g] : 0;
        myv[q] = v; mySum += v;
    }
    tot[t] = mySum;
    __syncthreads();
    for (int o = 1; o < 256; o <<= 1) {
        int u = (t >= o) ? tot[t - o] : 0;
        __syncthreads();
        tot[t] += u;
        __syncthreads();
    }
    int run = tot[t] - mySum;
    for (int q = 0; q < 4; q++) {
        int g = t * 4 + q;
        if (g < n) start[g] = run;
        run += myv[q];
    }
}

__global__ void k_scan_relblk(const int* __restrict__ start_rel, const int* __restrict__ blkhist,
                              int* __restrict__ blkbase) {
    int r = blockIdx.x * 256 + threadIdx.x;
    if (r >= N_RELS) return;
    int run = start_rel[r];
    for (int b = 0; b < NB_E; b++) {
        int v = blkhist[b * N_RELS + r];
        blkbase[b * N_RELS + r] = run;
        run += v;
    }
}

// ---------------------------------------------------------------------------
// K5: scatter payloads. pay_src[p]={dst,rel} (src-sorted); pay_rel[q]={src,dst}
// (rel-sorted, no global atomics via per-block bases).
// ---------------------------------------------------------------------------
__global__ __launch_bounds__(256) void k_scatter(const int* __restrict__ src, const int* __restrict__ dst,
        const int* __restrict__ rel, int* __restrict__ ctr_src,
        const int* __restrict__ blkbase, int2* __restrict__ pay_src, int2* __restrict__ pay_rel) {
    __shared__ int lbase[N_RELS];
    __shared__ int loff[N_RELS];
    int t = threadIdx.x;
    for (int r = t; r < N_RELS; r += 256) { lbase[r] = blkbase[blockIdx.x * N_RELS + r]; loff[r] = 0; }
    __syncthreads();
    int base = blockIdx.x * SC_EDGES;
    int end = min(base + SC_EDGES, N_EDGES);
    for (int g = base + t; g < end; g += 256) {
        int s = src[g], d = dst[g], r = rel[g];
        int p = atomicAdd(&ctr_src[s], 1);
        pay_src[p] = make_int2(d, r);
        int q = lbase[r] + atomicAdd(&loff[r], 1);
        pay_rel[q] = make_int2(s, d);
    }
}

// ---------------------------------------------------------------------------
// K6: fused scatter-softmax + neighbor aggregation. Wave per source node.
// ---------------------------------------------------------------------------
__global__ __launch_bounds__(256) void k_attn(const int2* __restrict__ pay,
        const int* __restrict__ start_src, const int* __restrict__ cnt_src,
        const float* __restrict__ us, const float* __restrict__ vs,
        const float* __restrict__ wsr, const float* __restrict__ V,
        const float* __restrict__ Wr, const float* __restrict__ b_a_p,
        float* __restrict__ h) {
    int lane = threadIdx.x & 63;
    int wv = threadIdx.x >> 6;
    int n = blockIdx.x * 4 + wv;
    if (n >= N_NODES) return;
    int st = start_src[n];
    int cnt = cnt_src[n];
    if (cnt == 0) { h[(size_t)n * 64 + lane] = 0.f; return; }
    float ba = b_a_p[0];
    float usn = us[n];

    if (cnt <= 64) {
        int2 pe = (lane < cnt) ? pay[st + lane] : make_int2(0, 0);
        float bexp = 0.f;
        if (lane < cnt) {
            float s = usn + vs[pe.x] + wsr[pe.y] + ba;
            s = s > 0.f ? s : SLOPE * s;
            bexp = expf(s);
        }
        float bp = bexp;
        #pragma unroll
        for (int o = 32; o; o >>= 1) bp += __shfl_xor(bp, o, 64);
        float inv = 1.f / bp;
        int sub = lane >> 4;
        int li = lane & 15;
        float4 acc = make_float4(0.f, 0.f, 0.f, 0.f);
        int groups = (cnt + 3) >> 2;
        for (int g = 0; g < groups; g++) {
            int esel = 4 * g + sub;
            float be = __shfl(bexp, esel, 64);
            int de = __shfl(pe.x, esel, 64);
            int re = __shfl(pe.y, esel, 64);
            float4 vv = *(const float4*)(V + (size_t)de * 64 + li * 4);
            float4 wvv = *(const float4*)(Wr + (size_t)re * 64 + li * 4);
            acc.x += be * (vv.x + wvv.x);
            acc.y += be * (vv.y + wvv.y);
            acc.z += be * (vv.z + wvv.z);
            acc.w += be * (vv.w + wvv.w);
        }
        acc.x += __shfl_xor(acc.x, 16, 64); acc.x += __shfl_xor(acc.x, 32, 64);
        acc.y += __shfl_xor(acc.y, 16, 64); acc.y += __shfl_xor(acc.y, 32, 64);
        acc.z += __shfl_xor(acc.z, 16, 64); acc.z += __shfl_xor(acc.z, 32, 64);
        acc.w += __shfl_xor(acc.w, 16, 64); acc.w += __shfl_xor(acc.w, 32, 64);
        if (lane < 16) {
            float4 u = *(const float4*)(h + (size_t)n * 64 + lane * 4);
            float4 o4;
            o4.x = u.x + acc.x * inv;
            o4.y = u.y + acc.y * inv;
            o4.z = u.z + acc.z * inv;
            o4.w = u.w + acc.w * inv;
            *(float4*)(h + (size_t)n * 64 + lane * 4) = o4;
        }
        return;
    }

    float bp = 0.f;
    for (int k = lane; k < cnt; k += 64) {
        int2 p = pay[st + k];
        float s = usn + vs[p.x] + wsr[p.y] + ba;
        s = s > 0.f ? s : SLOPE * s;
        bp += expf(s);
    }
    #pragma unroll
    for (int o = 32; o; o >>= 1) bp += __shfl_xor(bp, o, 64);
    float inv = 1.f / bp;
    float acc = 0.f;
    for (int k = 0; k < cnt; k++) {
        int2 p = pay[st + k];
        float s = usn + vs[p.x] + wsr[p.y] + ba;
        s = s > 0.f ? s : SLOPE * s;
        float b = expf(s);
        acc += b * (V[(size_t)p.x * 64 + lane] + Wr[(size_t)p.y * 64 + lane]);
    }
    float u = h[(size_t)n * 64 + lane];
    h[(size_t)n * 64 + lane] = u + acc * inv;
}

// ---------------------------------------------------------------------------
// K7: relation pooling (float4 gathers, pipelined pay prefetch, LDS reduce).
// ---------------------------------------------------------------------------
__global__ __launch_bounds__(256) void k_relpool(const int2* __restrict__ pay,
        const int* __restrict__ start_rel, const int* __restrict__ cnt_rel,
        const float* __restrict__ h, float* __restrict__ acc_rel) {
    int r = blockIdx.x / RSUB;
    int sub = blockIdx.x % RSUB;
    int st = start_rel[r];
    int cnt = cnt_rel[r];
    int t = threadIdx.x;
    int j = t >> 5;
    int side = (t >> 4) & 1;
    int li = t & 15;

    int chunk = (cnt + RSUB - 1) / RSUB;
    int k0 = sub * chunk;
    int k1 = min(k0 + chunk, cnt);
    int len = k1 - k0;

    float4 acc = make_float4(0.f, 0.f, 0.f, 0.f);
    if (len > 0) {
        int steps = (len + 7) >> 3;
        int k = k0 + j;
        bool v = (j < len);
        int2 p = v ? pay[st + k] : make_int2(0, 0);
        for (int it = 0; it < steps; it++) {
            k += 8;
            bool vn = (it + 1 < steps) && (k < k1);
            int2 pn = vn ? pay[st + k] : make_int2(0, 0);
            int idx = side ? p.y : p.x;
            float4 hv = *(const float4*)(h + (size_t)idx * 64 + li * 4);
            if (v) {
                acc.x += hv.x; acc.y += hv.y; acc.z += hv.z; acc.w += hv.w;
            }
            p = pn; v = vn;
        }
    }
    __shared__ float4 red[256];
    red[t] = acc;
    __syncthreads();
    if (t < 128) {
        float4 a = red[t], b = red[t + 128];
        a.x += b.x; a.y += b.y; a.z += b.z; a.w += b.w;
        red[t] = a;
    }
    __syncthreads();
    if (t < 64) {
        float4 a = red[t], b = red[t + 64];
        a.x += b.x; a.y += b.y; a.z += b.z; a.w += b.w;
        red[t] = a;
    }
    __syncthreads();
    if (t < 32) {
        float4 a = red[t], b = red[t + 32];
        a.x += b.x; a.y += b.y; a.z += b.z; a.w += b.w;
        float* dstp = &acc_rel[r * 128 + side * 64 + li * 4];
        atomicAdd(dstp + 0, a.x);
        atomicAdd(dstp + 1, a.y);
        atomicAdd(dstp + 2, a.z);
        atomicAdd(dstp + 3, a.w);
    }
}

// K8: mean + h_rel = mean @ W_rel3.T + b_rel3
__global__ void k_relfin(const float* __restrict__ acc_rel, const int* __restrict__ cnt_rel,
                         const float* __restrict__ Qr, const float* __restrict__ W_rel3,
                         const float* __restrict__ b_rel3, float* __restrict__ out) {
    int g = blockIdx.x * 256 + threadIdx.x;
    if (g >= N_RELS * 64) return;
    int r = g >> 6;
    int j = g & 63;
    int cnt = cnt_rel[r];
    float invc = 1.f / (float)(cnt > 0 ? cnt : 1);
    float s = b_rel3[j];
    for (int k = 0; k < 128; k++) s += acc_rel[r * 128 + k] * invc * W_rel3[j * 192 + k];
    if (cnt > 0)
        for (int k = 0; k < 64; k++) s += Qr[r * 64 + k] * W_rel3[j * 192 + 128 + k];
    out[g] = s;
}

extern "C" void kernel_launch(void* const* d_in, const int* in_sizes, int n_in,
                              void* d_out, int out_size, void* d_ws, size_t ws_size,
                              hipStream_t stream) {
    const float* ent    = (const float*)d_in[0];
    const float* relE   = (const float*)d_in[1];
    const float* W_ent  = (const float*)d_in[2];
    const float* b_ent  = (const float*)d_in[3];
    const float* W_relL = (const float*)d_in[4];
    const float* b_relL = (const float*)d_in[5];
    const float* W_rel2 = (const float*)d_in[6];
    const float* b_rel2 = (const float*)d_in[7];
    const float* W_rel3 = (const float*)d_in[8];
    const float* b_rel3 = (const float*)d_in[9];
    const float* W_a    = (const float*)d_in[10];
    const float* b_a    = (const float*)d_in[11];
    const float* W_fc   = (const float*)d_in[12];
    const float* b_fc   = (const float*)d_in[13];
    const int* src = (const int*)d_in[14];
    const int* dst = (const int*)d_in[15];
    const int* rel = (const int*)d_in[16];
    float* out = (float*)d_out;

    char* ws = (char*)d_ws;
    size_t off = 0;
    auto alloc = [&](size_t bytes) -> void* {
        void* p = ws + off;
        off += (bytes + 255) & ~(size_t)255;
        return p;
    };
    float* Wcat = (float*)alloc(8192 * 4);
    float* dcat = (float*)alloc(128 * 4);
    float* MW  = (float*)alloc(4096 * 4);
    float* MQ  = (float*)alloc(4096 * 4);
    float* dW  = (float*)alloc(64 * 4);
    float* dQ  = (float*)alloc(64 * 4);
    float* V   = (float*)alloc((size_t)N_NODES * 64 * 4);
    float* us  = (float*)alloc((size_t)N_NODES * 4);
    float* vs  = (float*)alloc((size_t)N_NODES * 4);
    float* Wr  = (float*)alloc((size_t)N_RELS * 64 * 4);
    float* Qr  = (float*)alloc((size_t)N_RELS * 64 * 4);
    float* wsr = (float*)alloc((size_t)N_RELS * 4);
    int* cnt_src   = (int*)alloc((size_t)N_NODES * 4);
    int* start_src = (int*)alloc((size_t)N_NODES * 4);
    int* ctr_src   = (int*)alloc((size_t)N_NODES * 4);
    int* partials  = (int*)alloc(256 * 4);
    int* cnt_rel   = (int*)alloc((size_t)N_RELS * 4);
    int* start_rel = (int*)alloc((size_t)N_RELS * 4);
    int* blkhist   = (int*)alloc((size_t)NB_E * N_RELS * 4);
    int* blkbase   = (int*)alloc((size_t)NB_E * N_RELS * 4);
    int2* pay_src  = (int2*)alloc((size_t)N_EDGES * 8);
    int2* pay_rel  = (int2*)alloc((size_t)N_EDGES * 8);
    float* acc_rel = (float*)alloc((size_t)N_RELS * 128 * 4);

    k_zero<<<(N_NODES + 255) / 256, 256, 0, stream>>>(cnt_src, N_NODES);
    k_zero<<<(N_RELS + 255) / 256, 256, 0, stream>>>(cnt_rel, N_RELS);
    k_zero<<<(N_RELS * 128 + 255) / 256, 256, 0, stream>>>((int*)acc_rel, N_RELS * 128);

    k_fold<<<65, 256, 0, stream>>>(W_ent, b_ent, W_relL, b_relL, W_rel2, b_rel2,
                                   W_fc, b_fc, Wcat, dcat, MW, MQ, dW, dQ);
    k_node<<<(N_NODES + 63) / 64, 256, 0, stream>>>(ent, Wcat, dcat, W_a, out, V, us, vs);
    k_relproj<<<125, 256, 0, stream>>>(relE, MW, MQ, dW, dQ, W_a, Wr, Qr, wsr);
    k_hist<<<NB_E, 256, 0, stream>>>(src, rel, cnt_src, cnt_rel, blkhist);
    k_scan_local<<<98, 256, 0, stream>>>(cnt_src, start_src, partials, N_NODES);
    k_scan_part<<<1, 256, 0, stream>>>(partials, 98);
    k_scan_add<<<(N_NODES + 255) / 256, 256, 0, stream>>>(start_src, partials, ctr_src, N_NODES);
    k_scan_small<<<1, 256, 0, stream>>>(cnt_rel, start_rel, N_RELS);
    k_scan_relblk<<<2, 256, 0, stream>>>(start_rel, blkhist, blkbase);
    k_scatter<<<NB_E, 256, 0, stream>>>(src, dst, rel, ctr_src, blkbase, pay_src, pay_rel);
    k_attn<<<N_NODES / 4, 256, 0, stream>>>(pay_src, start_src, cnt_src,
                                            us, vs, wsr, V, Wr, b_a, out);
    k_relpool<<<N_RELS * RSUB, 256, 0, stream>>>(pay_rel, start_rel, cnt_rel, out, acc_rel);
    k_relfin<<<(N_RELS * 64 + 255) / 256, 256, 0, stream>>>(acc_rel, cnt_rel, Qr, W_rel3,
                                                            b_rel3, out + (size_t)N_NODES * 64);
}